// Round 2
// baseline (457.821 us; speedup 1.0000x reference)
//
#include <hip/hip_runtime.h>
#include <hip/hip_bf16.h>
#include <stdint.h>

typedef short bf16x8 __attribute__((ext_vector_type(8)));
typedef float f32x4 __attribute__((ext_vector_type(4)));

__device__ __forceinline__ unsigned short f2bf(float f) {
  union { float f; unsigned int u; } v;
  v.f = f;
  unsigned int u = v.u;
  u = (u + 0x7fffu + ((u >> 16) & 1u)) >> 16;  // RNE
  return (unsigned short)u;
}

__device__ __forceinline__ float asf(unsigned int u) {
  union { unsigned int u; float f; } v; v.u = u; return v.f;
}

__device__ __forceinline__ unsigned int pack_bf16(float x, float y) {
  __hip_bfloat162 h = __float22bfloat162_rn(float2{x, y});
  union { __hip_bfloat162 h; unsigned int u; } cv; cv.h = h; return cv.u;
}

typedef union { bf16x8 v; unsigned int u[4]; } frag_u;

// ---------------------------------------------------------------------------
// Kernel 1: prep — x -> bf16, 7 weights -> transposed bf16 (Wt[n][k] = W[k][n])
// ---------------------------------------------------------------------------
__global__ __launch_bounds__(256) void prep_kernel(
    const float* __restrict__ x,
    const float* __restrict__ Wq, const float* __restrict__ Wk, const float* __restrict__ Wv,
    const float* __restrict__ Wfh, const float* __restrict__ Wfg,
    const float* __restrict__ Wrh, const float* __restrict__ Wrg,
    unsigned short* __restrict__ xb, unsigned short* __restrict__ wt) {
  int bid = blockIdx.x;
  int tid = threadIdx.x;
  if (bid < 448) {
    __shared__ float tile[64][65];
    int mat = bid >> 6;
    int t = bid & 63;
    int tr = (t >> 3) * 64, tc = (t & 7) * 64;
    const float* W = (mat == 0) ? Wq : (mat == 1) ? Wk : (mat == 2) ? Wv
                   : (mat == 3) ? Wfh : (mat == 4) ? Wfg : (mat == 5) ? Wrh : Wrg;
    unsigned short* Wt = wt + (size_t)mat * 512 * 512;
    for (int rep = 0; rep < 16; rep++) {
      int idx = rep * 256 + tid;
      int r = idx >> 6, c = idx & 63;
      tile[r][c] = W[(tr + r) * 512 + tc + c];
    }
    __syncthreads();
    for (int rep = 0; rep < 16; rep++) {
      int idx = rep * 256 + tid;
      int r = idx >> 6, c = idx & 63;
      Wt[(tc + r) * 512 + tr + c] = f2bf(tile[c][r]);
    }
  } else {
    int blk = bid - 448;
    const float4* xi = (const float4*)x;
    for (int rep = 0; rep < 32; rep++) {
      int i = blk * 256 + tid + rep * 16384;
      float4 v = xi[i];
      unsigned int lo = (unsigned int)f2bf(v.x) | ((unsigned int)f2bf(v.y) << 16);
      unsigned int hi = (unsigned int)f2bf(v.z) | ((unsigned int)f2bf(v.w) << 16);
      uint2 u; u.x = lo; u.y = hi;
      *(uint2*)&xb[(size_t)i * 4] = u;
    }
  }
}

// ---------------------------------------------------------------------------
// Kernel 2: QKV projection. 8 waves/block (4 m-subtiles x 2 n-halves) for
// 4 waves/SIMD occupancy. Q gets softmax scale folded. V written transposed.
// ---------------------------------------------------------------------------
__global__ __launch_bounds__(512) void qkv_kernel(
    const unsigned short* __restrict__ xb,
    const unsigned short* __restrict__ wtq, const unsigned short* __restrict__ wtk,
    const unsigned short* __restrict__ wtv,
    const float* __restrict__ bq, const float* __restrict__ bk, const float* __restrict__ bv,
    unsigned short* __restrict__ Qb, unsigned short* __restrict__ Kb,
    unsigned short* __restrict__ Vtb) {
  int mt = blockIdx.x;
  int nb = blockIdx.y;
  int w = threadIdx.x >> 6;
  int lane = threadIdx.x & 63;
  int c = lane & 15, quad = lane >> 4;
  int wsub = w & 3, nh = w >> 2;
  int row_a = mt * 64 + wsub * 16 + c;

  f32x4 aq[2], ak[2], av[2];
  f32x4 z4 = {0.f, 0.f, 0.f, 0.f};
  for (int i = 0; i < 2; i++) { aq[i] = z4; ak[i] = z4; av[i] = z4; }

  for (int kc = 0; kc < 512; kc += 32) {
    bf16x8 xa = *(const bf16x8*)&xb[(size_t)row_a * 512 + kc + quad * 8];
#pragma unroll
    for (int nt = 0; nt < 2; nt++) {
      int n = nb * 64 + nh * 32 + nt * 16 + c;
      bf16x8 fq = *(const bf16x8*)&wtq[(size_t)n * 512 + kc + quad * 8];
      bf16x8 fk = *(const bf16x8*)&wtk[(size_t)n * 512 + kc + quad * 8];
      bf16x8 fv = *(const bf16x8*)&wtv[(size_t)n * 512 + kc + quad * 8];
      aq[nt] = __builtin_amdgcn_mfma_f32_16x16x32_bf16(xa, fq, aq[nt], 0, 0, 0);
      ak[nt] = __builtin_amdgcn_mfma_f32_16x16x32_bf16(xa, fk, ak[nt], 0, 0, 0);
      av[nt] = __builtin_amdgcn_mfma_f32_16x16x32_bf16(xa, fv, av[nt], 0, 0, 0);
    }
  }

#pragma unroll
  for (int nt = 0; nt < 2; nt++) {
    int n = nb * 64 + nh * 32 + nt * 16 + c;
    float biasq = bq[n], biask = bk[n], biasv = bv[n];
    int h = n >> 6, d = n & 63;
    unsigned short vp[4];
#pragma unroll
    for (int r = 0; r < 4; r++) {
      int t = mt * 64 + wsub * 16 + quad * 4 + r;
      Qb[(size_t)t * 512 + n] = f2bf((aq[nt][r] + biasq) * 0.125f);
      Kb[(size_t)t * 512 + n] = f2bf(ak[nt][r] + biask);
      vp[r] = f2bf(av[nt][r] + biasv);
    }
    int t0 = mt * 64 + wsub * 16 + quad * 4;
    int bb = t0 >> 10;
    int tb = t0 & 1023;
    uint2 u;
    u.x = (unsigned int)vp[0] | ((unsigned int)vp[1] << 16);
    u.y = (unsigned int)vp[2] | ((unsigned int)vp[3] << 16);
    *(uint2*)&Vtb[((size_t)(bb * 8 + h) * 64 + d) * 1024 + tb] = u;
  }
}

// ---------------------------------------------------------------------------
// Kernel 3: fused complementary attention, barrier-free main loop.
// grid (64 qtiles, 4 batches), 256 threads = 4 waves (wave = k-stride).
// Phase 0: Z[h][q] (wave handles 2 heads), 1 barrier.
// Main: per wave, per 16-k tile: S for all 8 heads (A=K,B=Q so lane holds
//   all heads' scores for its (q,k)); masks in-lane (z<=0 / z>=0); P packed
//   into lo-half of K=32 frags (hi zeroed) matching V frags; PV MFMA.
// Tail: LDS atomic reduce over the 4 k-stride waves, normalize, transpose,
//   coalesced store.
// ---------------------------------------------------------------------------
__global__ __launch_bounds__(256, 1) void attn_kernel(
    const unsigned short* __restrict__ Qb, const unsigned short* __restrict__ Kb,
    const unsigned short* __restrict__ Vtb,
    const float* __restrict__ conv_w, const float* __restrict__ conv_b,
    unsigned short* __restrict__ Tfb, unsigned short* __restrict__ Trb) {
  const int qt = blockIdx.x;
  const int b  = blockIdx.y;
  const int tid = threadIdx.x;
  const int w = tid >> 6;
  const int lane = tid & 63;
  const int c = lane & 15, quad = lane >> 4;
  const int q0g = qt * 16;

  __shared__ float Zl[8][16];
  __shared__ float zbuf[256];                                   // [br][h][q]
  __shared__ __attribute__((aligned(16))) float accbuf[512 * 20]; // row=(h*4+dm)*16+dloc (pad 20), col q
  __shared__ __attribute__((aligned(16))) unsigned short trans[16][520];

  if (tid < 256) zbuf[tid] = 0.f;

  f32x4 z4 = {0.f, 0.f, 0.f, 0.f};

  // ---- phase 0: Z per (h,q). wave w handles heads w and w+4. ----
  for (int hh = 0; hh < 2; hh++) {
    int h = w + hh * 4;
    size_t qrow = (size_t)(b * 1024 + q0g + c) * 512 + h * 64;
    bf16x8 aq0 = *(const bf16x8*)&Qb[qrow + quad * 8];
    bf16x8 aq1 = *(const bf16x8*)&Qb[qrow + 32 + quad * 8];
    float zp[4] = {0.f, 0.f, 0.f, 0.f};
    for (int kt = 0; kt < 64; kt++) {
      size_t krow = (size_t)(b * 1024 + kt * 16 + c) * 512 + h * 64;
      bf16x8 bk0 = *(const bf16x8*)&Kb[krow + quad * 8];
      bf16x8 bk1 = *(const bf16x8*)&Kb[krow + 32 + quad * 8];
      f32x4 s = __builtin_amdgcn_mfma_f32_16x16x32_bf16(aq0, bk0, z4, 0, 0, 0);
      s = __builtin_amdgcn_mfma_f32_16x16x32_bf16(aq1, bk1, s, 0, 0, 0);
      zp[0] += __expf(s[0]); zp[1] += __expf(s[1]);
      zp[2] += __expf(s[2]); zp[3] += __expf(s[3]);
    }
#pragma unroll
    for (int r = 0; r < 4; r++) {
      float z = zp[r];
      z += __shfl_xor(z, 1); z += __shfl_xor(z, 2);
      z += __shfl_xor(z, 4); z += __shfl_xor(z, 8);
      if (c == r) Zl[h][quad * 4 + r] = z;
    }
  }
  __syncthreads();

  float invZ[8];
#pragma unroll
  for (int h = 0; h < 8; h++) invZ[h] = 1.0f / Zl[h][c];
  float cw[8];
#pragma unroll
  for (int h = 0; h < 8; h++) cw[h] = conv_w[h];
  const float cb = conv_b[0];

  f32x4 accf[8][4], accr[8][4];
#pragma unroll
  for (int h = 0; h < 8; h++)
#pragma unroll
    for (int dm = 0; dm < 4; dm++) { accf[h][dm] = z4; accr[h][dm] = z4; }
  float zaccf[8] = {0,0,0,0,0,0,0,0}, zaccr[8] = {0,0,0,0,0,0,0,0};

  const size_t qbase = (size_t)(b * 1024 + q0g + c) * 512;
  const size_t kbase = (size_t)(b * 1024 + c) * 512;

  // ---- main loop: wave w covers kt = w, w+4, ... (16 tiles of 16 k) ----
  for (int i = 0; i < 16; i++) {
    int k0 = (i * 4 + w) * 16;
    f32x4 a[8];
#pragma unroll
    for (int h = 0; h < 8; h++) {
      size_t krow = kbase + (size_t)k0 * 512 + h * 64;
      bf16x8 kf0 = *(const bf16x8*)&Kb[krow + quad * 8];
      bf16x8 kf1 = *(const bf16x8*)&Kb[krow + 32 + quad * 8];
      bf16x8 qf0 = *(const bf16x8*)&Qb[qbase + h * 64 + quad * 8];
      bf16x8 qf1 = *(const bf16x8*)&Qb[qbase + h * 64 + 32 + quad * 8];
      f32x4 s = __builtin_amdgcn_mfma_f32_16x16x32_bf16(kf0, qf0, z4, 0, 0, 0);
      s = __builtin_amdgcn_mfma_f32_16x16x32_bf16(kf1, qf1, s, 0, 0, 0);
#pragma unroll
      for (int r = 0; r < 4; r++) a[h][r] = __expf(s[r]) * invZ[h];
    }
    // cross-head gate, fully in-lane (lane holds all 8 heads at its (q,k)s)
    f32x4 zc = {cb, cb, cb, cb};
#pragma unroll
    for (int h = 0; h < 8; h++) {
      zc[0] += cw[h] * a[h][0]; zc[1] += cw[h] * a[h][1];
      zc[2] += cw[h] * a[h][2]; zc[3] += cw[h] * a[h][3];
    }
    bool mf[4], mr[4];
#pragma unroll
    for (int r = 0; r < 4; r++) { mf[r] = (zc[r] <= 0.f); mr[r] = (zc[r] >= 0.f); }

#pragma unroll
    for (int h = 0; h < 8; h++) {
      float ea0 = __expf(a[h][0]), ea1 = __expf(a[h][1]);
      float ea2 = __expf(a[h][2]), ea3 = __expf(a[h][3]);
      frag_u pF, pR;
      pF.u[0] = pack_bf16(mf[0] ? ea0 : 1.f, mf[1] ? ea1 : 1.f);
      pF.u[1] = pack_bf16(mf[2] ? ea2 : 1.f, mf[3] ? ea3 : 1.f);
      pF.u[2] = 0; pF.u[3] = 0;
      pR.u[0] = pack_bf16(mr[0] ? ea0 : 1.f, mr[1] ? ea1 : 1.f);
      pR.u[1] = pack_bf16(mr[2] ? ea2 : 1.f, mr[3] ? ea3 : 1.f);
      pR.u[2] = 0; pR.u[3] = 0;
      // denominators from the bf16-rounded values (exactly match numerator)
      zaccf[h] += asf(pF.u[0] << 16) + asf(pF.u[0] & 0xffff0000u)
                + asf(pF.u[1] << 16) + asf(pF.u[1] & 0xffff0000u);
      zaccr[h] += asf(pR.u[0] << 16) + asf(pR.u[0] & 0xffff0000u)
                + asf(pR.u[1] << 16) + asf(pR.u[1] & 0xffff0000u);
      size_t vrow = ((size_t)((b * 8 + h) * 64) + c) * 1024 + k0 + quad * 4;
#pragma unroll
      for (int dm = 0; dm < 4; dm++) {
        frag_u vf;
        uint2 vv = *(const uint2*)&Vtb[vrow + (size_t)dm * 16 * 1024];
        vf.u[0] = vv.x; vf.u[1] = vv.y; vf.u[2] = 0; vf.u[3] = 0;
        accf[h][dm] = __builtin_amdgcn_mfma_f32_16x16x32_bf16(vf.v, pF.v, accf[h][dm], 0, 0, 0);
        accr[h][dm] = __builtin_amdgcn_mfma_f32_16x16x32_bf16(vf.v, pR.v, accr[h][dm], 0, 0, 0);
      }
    }
  }

  // ---- tail: reduce z across quads + waves ----
#pragma unroll
  for (int h = 0; h < 8; h++) {
    float zf = zaccf[h]; zf += __shfl_xor(zf, 16); zf += __shfl_xor(zf, 32);
    float zr = zaccr[h]; zr += __shfl_xor(zr, 16); zr += __shfl_xor(zr, 32);
    if (lane < 16) {
      atomicAdd(&zbuf[h * 16 + c], zf);
      atomicAdd(&zbuf[128 + h * 16 + c], zr);
    }
  }
  __syncthreads();
  if (tid < 256) zbuf[tid] = 1.0f / zbuf[tid];

  for (int br = 0; br < 2; br++) {
    for (int j = tid; j < 512 * 20; j += 256) accbuf[j] = 0.f;
    __syncthreads();
#pragma unroll
    for (int h = 0; h < 8; h++)
#pragma unroll
      for (int dm = 0; dm < 4; dm++) {
        f32x4 v = (br == 0) ? accf[h][dm] : accr[h][dm];
        int rowb = (h * 4 + dm) * 16 + quad * 4;
#pragma unroll
        for (int r = 0; r < 4; r++) atomicAdd(&accbuf[(rowb + r) * 20 + c], v[r]);
      }
    __syncthreads();
    // normalize + transpose (row index == output column h*64+dm*16+dloc)
#pragma unroll
    for (int rep = 0; rep < 8; rep++) {
      int vecid = rep * 256 + tid;
      int row = vecid >> 2;
      int qv = (vecid & 3) * 4;
      f32x4 v = *(f32x4*)&accbuf[row * 20 + qv];
      int h = row >> 6;
      f32x4 iz = *(f32x4*)&zbuf[br * 128 + h * 16 + qv];
#pragma unroll
      for (int r = 0; r < 4; r++) trans[qv + r][row] = f2bf(v[r] * iz[r]);
    }
    __syncthreads();
    unsigned short* dst = (br == 0) ? Tfb : Trb;
    {
      int rowq = tid >> 4, seg = tid & 15;
      size_t gbase = (size_t)(b * 1024 + q0g + rowq) * 512 + seg * 32;
#pragma unroll
      for (int ii = 0; ii < 4; ii++) {
        *(uint4*)&dst[gbase + ii * 8] = *(uint4*)&trans[rowq][seg * 32 + ii * 8];
      }
    }
    __syncthreads();
  }
}

// ---------------------------------------------------------------------------
// Kernel 4: fused output projections + gate combine. 8 waves/block.
// ---------------------------------------------------------------------------
__global__ __launch_bounds__(512) void final_kernel(
    const unsigned short* __restrict__ Tfb, const unsigned short* __restrict__ Trb,
    const unsigned short* __restrict__ wfh, const unsigned short* __restrict__ wfg,
    const unsigned short* __restrict__ wrh, const unsigned short* __restrict__ wrg,
    const float* __restrict__ bfh, const float* __restrict__ bfg,
    const float* __restrict__ brh, const float* __restrict__ brg,
    float* __restrict__ out) {
  int mt = blockIdx.x;
  int nb = blockIdx.y;
  int w = threadIdx.x >> 6;
  int lane = threadIdx.x & 63;
  int c = lane & 15, quad = lane >> 4;
  int wsub = w & 3, nh = w >> 2;
  int row_a = mt * 64 + wsub * 16 + c;

  f32x4 aFh[2], aFg[2], aRh[2], aRg[2];
  f32x4 z4 = {0.f, 0.f, 0.f, 0.f};
  for (int i = 0; i < 2; i++) { aFh[i] = z4; aFg[i] = z4; aRh[i] = z4; aRg[i] = z4; }

  for (int kc = 0; kc < 512; kc += 32) {
    bf16x8 tf = *(const bf16x8*)&Tfb[(size_t)row_a * 512 + kc + quad * 8];
    bf16x8 tr = *(const bf16x8*)&Trb[(size_t)row_a * 512 + kc + quad * 8];
#pragma unroll
    for (int nt = 0; nt < 2; nt++) {
      int n = nb * 64 + nh * 32 + nt * 16 + c;
      bf16x8 f0 = *(const bf16x8*)&wfh[(size_t)n * 512 + kc + quad * 8];
      bf16x8 f1 = *(const bf16x8*)&wfg[(size_t)n * 512 + kc + quad * 8];
      bf16x8 f2 = *(const bf16x8*)&wrh[(size_t)n * 512 + kc + quad * 8];
      bf16x8 f3 = *(const bf16x8*)&wrg[(size_t)n * 512 + kc + quad * 8];
      aFh[nt] = __builtin_amdgcn_mfma_f32_16x16x32_bf16(tf, f0, aFh[nt], 0, 0, 0);
      aFg[nt] = __builtin_amdgcn_mfma_f32_16x16x32_bf16(tf, f1, aFg[nt], 0, 0, 0);
      aRh[nt] = __builtin_amdgcn_mfma_f32_16x16x32_bf16(tr, f2, aRh[nt], 0, 0, 0);
      aRg[nt] = __builtin_amdgcn_mfma_f32_16x16x32_bf16(tr, f3, aRg[nt], 0, 0, 0);
    }
  }

#pragma unroll
  for (int nt = 0; nt < 2; nt++) {
    int n = nb * 64 + nh * 32 + nt * 16 + c;
    float b0 = bfh[n], b1 = bfg[n], b2 = brh[n], b3 = brg[n];
#pragma unroll
    for (int r = 0; r < 4; r++) {
      int t = mt * 64 + wsub * 16 + quad * 4 + r;
      float Ff = aFh[nt][r] + b0;
      float Gf = 1.0f / (1.0f + __expf(-(aFg[nt][r] + b1)));
      float Fr = aRh[nt][r] + b2;
      float Gr = 1.0f / (1.0f + __expf(-(aRg[nt][r] + b3)));
      float ef = __expf(Gf), er = __expf(Gr);
      out[(size_t)t * 512 + n] = (Ff * ef + Fr * er) / (ef + er);
    }
  }
}

// ---------------------------------------------------------------------------
// Launch. Workspace layout (bytes):
//   0: xb 4MB | 4MB: Qb 4MB | 8MB: Kb 4MB | 12MB: Vtb 4MB
//   16MB: Tfb 4MB | 20MB: Trb 4MB | 24MB: 7x transposed bf16 weights (3.5MB)
// ---------------------------------------------------------------------------
extern "C" void kernel_launch(void* const* d_in, const int* in_sizes, int n_in,
                              void* d_out, int out_size, void* d_ws, size_t ws_size,
                              hipStream_t stream) {
  const float* x   = (const float*)d_in[0];
  const float* Wq  = (const float*)d_in[1];
  const float* bq  = (const float*)d_in[2];
  const float* Wk  = (const float*)d_in[3];
  const float* bk  = (const float*)d_in[4];
  const float* Wv  = (const float*)d_in[5];
  const float* bv  = (const float*)d_in[6];
  const float* cw  = (const float*)d_in[7];
  const float* cb  = (const float*)d_in[8];
  const float* Wfh = (const float*)d_in[9];
  const float* bfh = (const float*)d_in[10];
  const float* Wfg = (const float*)d_in[11];
  const float* bfg = (const float*)d_in[12];
  const float* Wrh = (const float*)d_in[13];
  const float* brh = (const float*)d_in[14];
  const float* Wrg = (const float*)d_in[15];
  const float* brg = (const float*)d_in[16];

  char* ws = (char*)d_ws;
  const size_t MB = 1024 * 1024;
  unsigned short* xb  = (unsigned short*)(ws + 0 * MB);
  unsigned short* Qb  = (unsigned short*)(ws + 4 * MB);
  unsigned short* Kb  = (unsigned short*)(ws + 8 * MB);
  unsigned short* Vtb = (unsigned short*)(ws + 12 * MB);
  unsigned short* Tfb = (unsigned short*)(ws + 16 * MB);
  unsigned short* Trb = (unsigned short*)(ws + 20 * MB);
  unsigned short* wt  = (unsigned short*)(ws + 24 * MB);
  const size_t WSZ = 512 * 512;

  prep_kernel<<<512, 256, 0, stream>>>(x, Wq, Wk, Wv, Wfh, Wfg, Wrh, Wrg, xb, wt);
  qkv_kernel<<<dim3(64, 8), 512, 0, stream>>>(xb, wt + 0 * WSZ, wt + 1 * WSZ, wt + 2 * WSZ,
                                              bq, bk, bv, Qb, Kb, Vtb);
  attn_kernel<<<dim3(64, 4), 256, 0, stream>>>(Qb, Kb, Vtb, cw, cb, Tfb, Trb);
  final_kernel<<<dim3(64, 8), 512, 0, stream>>>(Tfb, Trb, wt + 3 * WSZ, wt + 4 * WSZ,
                                                wt + 5 * WSZ, wt + 6 * WSZ,
                                                bfh, bfg, brh, brg, (float*)d_out);
}

// Round 3
// 336.358 us; speedup vs baseline: 1.3611x; 1.3611x over previous
//
#include <hip/hip_runtime.h>
#include <hip/hip_bf16.h>
#include <stdint.h>

typedef short bf16x8 __attribute__((ext_vector_type(8)));
typedef float f32x4 __attribute__((ext_vector_type(4)));

__device__ __forceinline__ unsigned short f2bf(float f) {
  union { float f; unsigned int u; } v;
  v.f = f;
  unsigned int u = v.u;
  u = (u + 0x7fffu + ((u >> 16) & 1u)) >> 16;  // RNE
  return (unsigned short)u;
}

__device__ __forceinline__ float asf(unsigned int u) {
  union { unsigned int u; float f; } v; v.u = u; return v.f;
}

__device__ __forceinline__ unsigned int pack_bf16(float x, float y) {
  return (unsigned int)f2bf(x) | ((unsigned int)f2bf(y) << 16);
}

typedef union { bf16x8 v; unsigned int u[4]; } frag_u;

// global->LDS async copy, 16B per lane. LDS dest = wave-uniform base + lane*16.
__device__ __forceinline__ void gload16(const void* g, void* lds) {
  __builtin_amdgcn_global_load_lds(
      (const __attribute__((address_space(1))) unsigned int*)(unsigned long long)g,
      (__attribute__((address_space(3))) unsigned int*)(unsigned long long)(unsigned)(unsigned long long)lds,
      16, 0, 0);
}

// Read a bf16x8 fragment from a 64x64 tile whose 16B chunks are XOR-swizzled:
// chunk j of row r stored at position j ^ (r&7).
__device__ __forceinline__ bf16x8 lds_frag(const unsigned short* t, int row, int ch4q) {
  return *(const bf16x8*)(t + row * 64 + ((ch4q ^ (row & 7)) << 3));
}

// ---------------------------------------------------------------------------
// Kernel 1: prep — x -> bf16, 7 weights -> transposed bf16 (Wt[n][k] = W[k][n])
// ---------------------------------------------------------------------------
__global__ __launch_bounds__(256) void prep_kernel(
    const float* __restrict__ x,
    const float* __restrict__ Wq, const float* __restrict__ Wk, const float* __restrict__ Wv,
    const float* __restrict__ Wfh, const float* __restrict__ Wfg,
    const float* __restrict__ Wrh, const float* __restrict__ Wrg,
    unsigned short* __restrict__ xb, unsigned short* __restrict__ wt) {
  int bid = blockIdx.x;
  int tid = threadIdx.x;
  if (bid < 448) {
    __shared__ float tile[64][65];
    int mat = bid >> 6;
    int t = bid & 63;
    int tr = (t >> 3) * 64, tc = (t & 7) * 64;
    const float* W = (mat == 0) ? Wq : (mat == 1) ? Wk : (mat == 2) ? Wv
                   : (mat == 3) ? Wfh : (mat == 4) ? Wfg : (mat == 5) ? Wrh : Wrg;
    unsigned short* Wt = wt + (size_t)mat * 512 * 512;
    for (int rep = 0; rep < 16; rep++) {
      int idx = rep * 256 + tid;
      int r = idx >> 6, c = idx & 63;
      tile[r][c] = W[(tr + r) * 512 + tc + c];
    }
    __syncthreads();
    for (int rep = 0; rep < 16; rep++) {
      int idx = rep * 256 + tid;
      int r = idx >> 6, c = idx & 63;
      Wt[(tc + r) * 512 + tr + c] = f2bf(tile[c][r]);
    }
  } else {
    int blk = bid - 448;
    const float4* xi = (const float4*)x;
    for (int rep = 0; rep < 32; rep++) {
      int i = blk * 256 + tid + rep * 16384;
      float4 v = xi[i];
      unsigned int lo = (unsigned int)f2bf(v.x) | ((unsigned int)f2bf(v.y) << 16);
      unsigned int hi = (unsigned int)f2bf(v.z) | ((unsigned int)f2bf(v.w) << 16);
      uint2 u; u.x = lo; u.y = hi;
      *(uint2*)&xb[(size_t)i * 4] = u;
    }
  }
}

// ---------------------------------------------------------------------------
// Kernel 2: QKV projection, LDS-staged GEMM. Block 64m x 64n, 4 waves (2x2),
// wave = 32m x 32n, K-step 64, global_load_lds staging, swizzled chunks.
// Q gets softmax scale folded. V written transposed for PV A-fragments.
// ---------------------------------------------------------------------------
__global__ __launch_bounds__(256, 2) void qkv_kernel(
    const unsigned short* __restrict__ xb,
    const unsigned short* __restrict__ wtq, const unsigned short* __restrict__ wtk,
    const unsigned short* __restrict__ wtv,
    const float* __restrict__ bq, const float* __restrict__ bk, const float* __restrict__ bv,
    unsigned short* __restrict__ Qb, unsigned short* __restrict__ Kb,
    unsigned short* __restrict__ Vtb) {
  __shared__ unsigned short As[64 * 64];
  __shared__ unsigned short Bq[64 * 64];
  __shared__ unsigned short Bk[64 * 64];
  __shared__ unsigned short Bv[64 * 64];
  const int m0 = blockIdx.x * 64, n0 = blockIdx.y * 64;
  const int tid = threadIdx.x, w = tid >> 6, lane = tid & 63;
  const int c = lane & 15, quad = lane >> 4;
  const int wm = w & 1, wn = w >> 1;
  const int rsel = lane >> 3, csel = lane & 7;
  const int sc = csel ^ rsel;  // stage swizzle (row&7 == rsel here)
  const char* Ag  = (const char*)xb  + (size_t)(m0 + w * 16 + rsel) * 1024 + sc * 16;
  const char* Bgq = (const char*)wtq + (size_t)(n0 + w * 16 + rsel) * 1024 + sc * 16;
  const char* Bgk = (const char*)wtk + (size_t)(n0 + w * 16 + rsel) * 1024 + sc * 16;
  const char* Bgv = (const char*)wtv + (size_t)(n0 + w * 16 + rsel) * 1024 + sc * 16;
  unsigned short* lA = &As[w * 1024];
  unsigned short* lQ = &Bq[w * 1024];
  unsigned short* lK = &Bk[w * 1024];
  unsigned short* lV = &Bv[w * 1024];

  f32x4 acc[3][2][2];
  f32x4 z4 = {0.f, 0.f, 0.f, 0.f};
#pragma unroll
  for (int o = 0; o < 3; o++)
#pragma unroll
    for (int i = 0; i < 2; i++)
#pragma unroll
      for (int j = 0; j < 2; j++) acc[o][i][j] = z4;

  for (int ks = 0; ks < 8; ks++) {
    if (ks) __syncthreads();
    const int kb = ks * 128;
    gload16(Ag + kb, lA);        gload16(Ag + kb + 8192, lA + 512);
    gload16(Bgq + kb, lQ);       gload16(Bgq + kb + 8192, lQ + 512);
    gload16(Bgk + kb, lK);       gload16(Bgk + kb + 8192, lK + 512);
    gload16(Bgv + kb, lV);       gload16(Bgv + kb + 8192, lV + 512);
    __syncthreads();
#pragma unroll
    for (int ch = 0; ch < 2; ch++) {
      const int cq = ch * 4 + quad;
      bf16x8 a0 = lds_frag(As, wm * 32 + c, cq);
      bf16x8 a1 = lds_frag(As, wm * 32 + 16 + c, cq);
#pragma unroll
      for (int nt = 0; nt < 2; nt++) {
        const int rb = wn * 32 + nt * 16 + c;
        bf16x8 fq = lds_frag(Bq, rb, cq);
        bf16x8 fk = lds_frag(Bk, rb, cq);
        bf16x8 fv = lds_frag(Bv, rb, cq);
        acc[0][0][nt] = __builtin_amdgcn_mfma_f32_16x16x32_bf16(a0, fq, acc[0][0][nt], 0, 0, 0);
        acc[0][1][nt] = __builtin_amdgcn_mfma_f32_16x16x32_bf16(a1, fq, acc[0][1][nt], 0, 0, 0);
        acc[1][0][nt] = __builtin_amdgcn_mfma_f32_16x16x32_bf16(a0, fk, acc[1][0][nt], 0, 0, 0);
        acc[1][1][nt] = __builtin_amdgcn_mfma_f32_16x16x32_bf16(a1, fk, acc[1][1][nt], 0, 0, 0);
        acc[2][0][nt] = __builtin_amdgcn_mfma_f32_16x16x32_bf16(a0, fv, acc[2][0][nt], 0, 0, 0);
        acc[2][1][nt] = __builtin_amdgcn_mfma_f32_16x16x32_bf16(a1, fv, acc[2][1][nt], 0, 0, 0);
      }
    }
  }

#pragma unroll
  for (int ms = 0; ms < 2; ms++)
#pragma unroll
    for (int nt = 0; nt < 2; nt++) {
      int n = n0 + wn * 32 + nt * 16 + c;
      float biasq = bq[n], biask = bk[n], biasv = bv[n];
      int h = n >> 6, d = n & 63;
      int t0 = m0 + wm * 32 + ms * 16 + quad * 4;
      unsigned short vp[4];
#pragma unroll
      for (int r = 0; r < 4; r++) {
        int t = t0 + r;
        Qb[(size_t)t * 512 + n] = f2bf((acc[0][ms][nt][r] + biasq) * 0.125f);
        Kb[(size_t)t * 512 + n] = f2bf(acc[1][ms][nt][r] + biask);
        vp[r] = f2bf(acc[2][ms][nt][r] + biasv);
      }
      int bb = t0 >> 10, tb = t0 & 1023;
      uint2 u;
      u.x = (unsigned int)vp[0] | ((unsigned int)vp[1] << 16);
      u.y = (unsigned int)vp[2] | ((unsigned int)vp[3] << 16);
      *(uint2*)&Vtb[((size_t)(bb * 8 + h) * 64 + d) * 1024 + tb] = u;
    }
}

// ---------------------------------------------------------------------------
// Kernel 3: zmask — per (b, 16q) block, 8 waves split k (128 each).
// Pass 1: Z[h][q] for all 8 heads. Pass 2: recompute s, cross-head gate
// (in-lane: A=K,B=Q puts q in col, k in row), write mask bytes + invZ.
// ---------------------------------------------------------------------------
__global__ __launch_bounds__(512, 2) void zmask_kernel(
    const unsigned short* __restrict__ Qb, const unsigned short* __restrict__ Kb,
    const float* __restrict__ conv_w, const float* __restrict__ conv_b,
    unsigned char* __restrict__ Mu8, float* __restrict__ invZg) {
  const int qt = blockIdx.x, b = blockIdx.y;
  const int q0 = qt * 16;
  const int tid = threadIdx.x, w = tid >> 6, lane = tid & 63;
  const int c = lane & 15, quad = lane >> 4;

  __shared__ float zl[8][16];
  if (tid < 128) ((float*)zl)[tid] = 0.f;
  __syncthreads();

  f32x4 z4 = {0.f, 0.f, 0.f, 0.f};
  const size_t qrow = (size_t)(b * 1024 + q0 + c) * 512;
  bf16x8 qf[8][2];
#pragma unroll
  for (int h = 0; h < 8; h++) {
    qf[h][0] = *(const bf16x8*)&Qb[qrow + h * 64 + quad * 8];
    qf[h][1] = *(const bf16x8*)&Qb[qrow + h * 64 + 32 + quad * 8];
  }

  // pass 1: partial Z over this wave's 128 k
  float zp[8] = {0, 0, 0, 0, 0, 0, 0, 0};
  for (int kt = 0; kt < 8; kt++) {
    const int kk = w * 128 + kt * 16;
    const size_t krow = (size_t)(b * 1024 + kk + c) * 512;
#pragma unroll
    for (int h = 0; h < 8; h++) {
      bf16x8 kf0 = *(const bf16x8*)&Kb[krow + h * 64 + quad * 8];
      bf16x8 kf1 = *(const bf16x8*)&Kb[krow + h * 64 + 32 + quad * 8];
      f32x4 s = __builtin_amdgcn_mfma_f32_16x16x32_bf16(kf0, qf[h][0], z4, 0, 0, 0);
      s = __builtin_amdgcn_mfma_f32_16x16x32_bf16(kf1, qf[h][1], s, 0, 0, 0);
      zp[h] += __expf(s[0]) + __expf(s[1]) + __expf(s[2]) + __expf(s[3]);
    }
  }
#pragma unroll
  for (int h = 0; h < 8; h++) {
    float z = zp[h];
    z += __shfl_xor(z, 16); z += __shfl_xor(z, 32);
    if (quad == 0) atomicAdd(&zl[h][c], z);
  }
  __syncthreads();

  float invZ[8];
#pragma unroll
  for (int h = 0; h < 8; h++) invZ[h] = 1.0f / zl[h][c];
  float cw[8];
#pragma unroll
  for (int h = 0; h < 8; h++) cw[h] = conv_w[h];
  const float cb = conv_b[0];

  // pass 2: gate + mask bytes
  for (int kt = 0; kt < 8; kt++) {
    const int kk = w * 128 + kt * 16;
    const size_t krow = (size_t)(b * 1024 + kk + c) * 512;
    f32x4 zc = {cb, cb, cb, cb};
#pragma unroll
    for (int h = 0; h < 8; h++) {
      bf16x8 kf0 = *(const bf16x8*)&Kb[krow + h * 64 + quad * 8];
      bf16x8 kf1 = *(const bf16x8*)&Kb[krow + h * 64 + 32 + quad * 8];
      f32x4 s = __builtin_amdgcn_mfma_f32_16x16x32_bf16(kf0, qf[h][0], z4, 0, 0, 0);
      s = __builtin_amdgcn_mfma_f32_16x16x32_bf16(kf1, qf[h][1], s, 0, 0, 0);
#pragma unroll
      for (int r = 0; r < 4; r++) zc[r] += cw[h] * (__expf(s[r]) * invZ[h]);
    }
    unsigned int packed = 0;
#pragma unroll
    for (int r = 0; r < 4; r++) {
      unsigned int m = (zc[r] <= 0.f ? 1u : 0u) | (zc[r] >= 0.f ? 2u : 0u);
      packed |= m << (8 * r);
    }
    *(unsigned int*)&Mu8[(size_t)(b * 1024 + q0 + c) * 1024 + kk + quad * 4] = packed;
  }

  if (tid < 128) {
    int hh = tid >> 4, qq = tid & 15;
    invZg[(size_t)(b * 8 + hh) * 1024 + q0 + qq] = 1.0f / zl[hh][qq];
  }
}

// ---------------------------------------------------------------------------
// Kernel 4: pv — per (b,h,64q) block, 4 waves split q (16 each). Barrier-free,
// LDS-free. Recompute s (A=K,B=Q), read mask bytes, half-frag PV MFMA with
// bf16-consistent denominators (round-2-proven math).
// ---------------------------------------------------------------------------
__global__ __launch_bounds__(256, 2) void pv_kernel(
    const unsigned short* __restrict__ Qb, const unsigned short* __restrict__ Kb,
    const unsigned short* __restrict__ Vtb,
    const unsigned char* __restrict__ Mu8, const float* __restrict__ invZg,
    unsigned short* __restrict__ Tfb, unsigned short* __restrict__ Trb) {
  const int qt = blockIdx.x, h = blockIdx.y, b = blockIdx.z;
  const int tid = threadIdx.x, w = tid >> 6, lane = tid & 63;
  const int c = lane & 15, quad = lane >> 4;
  const int q = qt * 64 + w * 16 + c;

  f32x4 z4 = {0.f, 0.f, 0.f, 0.f};
  const size_t qrow = (size_t)(b * 1024 + q) * 512 + h * 64;
  bf16x8 qf0 = *(const bf16x8*)&Qb[qrow + quad * 8];
  bf16x8 qf1 = *(const bf16x8*)&Qb[qrow + 32 + quad * 8];
  const float invZ = invZg[(size_t)(b * 8 + h) * 1024 + q];
  const size_t mrow = (size_t)(b * 1024 + q) * 1024;
  const size_t vbase = ((size_t)(b * 8 + h) * 64 + c) * 1024;

  f32x4 accf[4], accr[4];
#pragma unroll
  for (int i = 0; i < 4; i++) { accf[i] = z4; accr[i] = z4; }
  float zf = 0.f, zr = 0.f;

  for (int kt = 0; kt < 64; kt++) {
    const int k0 = kt * 16;
    const size_t krow = (size_t)(b * 1024 + k0 + c) * 512 + h * 64;
    bf16x8 kf0 = *(const bf16x8*)&Kb[krow + quad * 8];
    bf16x8 kf1 = *(const bf16x8*)&Kb[krow + 32 + quad * 8];
    f32x4 s = __builtin_amdgcn_mfma_f32_16x16x32_bf16(kf0, qf0, z4, 0, 0, 0);
    s = __builtin_amdgcn_mfma_f32_16x16x32_bf16(kf1, qf1, s, 0, 0, 0);
    const unsigned int mb = *(const unsigned int*)&Mu8[mrow + k0 + quad * 4];
    float ea[4];
#pragma unroll
    for (int r = 0; r < 4; r++) ea[r] = __expf(__expf(s[r]) * invZ);
    frag_u pF, pR;
    pF.u[0] = pack_bf16((mb & 0x1u) ? ea[0] : 1.f, (mb & 0x100u) ? ea[1] : 1.f);
    pF.u[1] = pack_bf16((mb & 0x10000u) ? ea[2] : 1.f, (mb & 0x1000000u) ? ea[3] : 1.f);
    pF.u[2] = 0; pF.u[3] = 0;
    pR.u[0] = pack_bf16((mb & 0x2u) ? ea[0] : 1.f, (mb & 0x200u) ? ea[1] : 1.f);
    pR.u[1] = pack_bf16((mb & 0x20000u) ? ea[2] : 1.f, (mb & 0x2000000u) ? ea[3] : 1.f);
    pR.u[2] = 0; pR.u[3] = 0;
    zf += asf(pF.u[0] << 16) + asf(pF.u[0] & 0xffff0000u)
        + asf(pF.u[1] << 16) + asf(pF.u[1] & 0xffff0000u);
    zr += asf(pR.u[0] << 16) + asf(pR.u[0] & 0xffff0000u)
        + asf(pR.u[1] << 16) + asf(pR.u[1] & 0xffff0000u);
#pragma unroll
    for (int dm = 0; dm < 4; dm++) {
      frag_u vf;
      uint2 vv = *(const uint2*)&Vtb[vbase + (size_t)dm * 16 * 1024 + k0 + quad * 4];
      vf.u[0] = vv.x; vf.u[1] = vv.y; vf.u[2] = 0; vf.u[3] = 0;
      accf[dm] = __builtin_amdgcn_mfma_f32_16x16x32_bf16(vf.v, pF.v, accf[dm], 0, 0, 0);
      accr[dm] = __builtin_amdgcn_mfma_f32_16x16x32_bf16(vf.v, pR.v, accr[dm], 0, 0, 0);
    }
  }

  zf += __shfl_xor(zf, 16); zf += __shfl_xor(zf, 32);
  zr += __shfl_xor(zr, 16); zr += __shfl_xor(zr, 32);
  const float izf = 1.0f / zf, izr = 1.0f / zr;
  const size_t trow = (size_t)(b * 1024 + q) * 512 + h * 64;
#pragma unroll
  for (int dm = 0; dm < 4; dm++) {
    uint2 u;
    u.x = pack_bf16(accf[dm][0] * izf, accf[dm][1] * izf);
    u.y = pack_bf16(accf[dm][2] * izf, accf[dm][3] * izf);
    *(uint2*)&Tfb[trow + dm * 16 + quad * 4] = u;
    u.x = pack_bf16(accr[dm][0] * izr, accr[dm][1] * izr);
    u.y = pack_bf16(accr[dm][2] * izr, accr[dm][3] * izr);
    *(uint2*)&Trb[trow + dm * 16 + quad * 4] = u;
  }
}

// ---------------------------------------------------------------------------
// Kernel 5: final — LDS-staged fused 4-GEMM + gate combine.
// ---------------------------------------------------------------------------
__global__ __launch_bounds__(256, 2) void final_kernel(
    const unsigned short* __restrict__ Tfb, const unsigned short* __restrict__ Trb,
    const unsigned short* __restrict__ wfh, const unsigned short* __restrict__ wfg,
    const unsigned short* __restrict__ wrh, const unsigned short* __restrict__ wrg,
    const float* __restrict__ bfh, const float* __restrict__ bfg,
    const float* __restrict__ brh, const float* __restrict__ brg,
    float* __restrict__ out) {
  __shared__ unsigned short Atf[64 * 64];
  __shared__ unsigned short Atr[64 * 64];
  __shared__ unsigned short Bfh[64 * 64];
  __shared__ unsigned short Bfg[64 * 64];
  __shared__ unsigned short Brh[64 * 64];
  __shared__ unsigned short Brg[64 * 64];
  const int m0 = blockIdx.x * 64, n0 = blockIdx.y * 64;
  const int tid = threadIdx.x, w = tid >> 6, lane = tid & 63;
  const int c = lane & 15, quad = lane >> 4;
  const int wm = w & 1, wn = w >> 1;
  const int rsel = lane >> 3, csel = lane & 7;
  const int sc = csel ^ rsel;
  const char* Agf = (const char*)Tfb + (size_t)(m0 + w * 16 + rsel) * 1024 + sc * 16;
  const char* Agr = (const char*)Trb + (size_t)(m0 + w * 16 + rsel) * 1024 + sc * 16;
  const char* Bg0 = (const char*)wfh + (size_t)(n0 + w * 16 + rsel) * 1024 + sc * 16;
  const char* Bg1 = (const char*)wfg + (size_t)(n0 + w * 16 + rsel) * 1024 + sc * 16;
  const char* Bg2 = (const char*)wrh + (size_t)(n0 + w * 16 + rsel) * 1024 + sc * 16;
  const char* Bg3 = (const char*)wrg + (size_t)(n0 + w * 16 + rsel) * 1024 + sc * 16;
  unsigned short* lAf = &Atf[w * 1024];
  unsigned short* lAr = &Atr[w * 1024];
  unsigned short* l0 = &Bfh[w * 1024];
  unsigned short* l1 = &Bfg[w * 1024];
  unsigned short* l2 = &Brh[w * 1024];
  unsigned short* l3 = &Brg[w * 1024];

  f32x4 acc[4][2][2];
  f32x4 z4 = {0.f, 0.f, 0.f, 0.f};
#pragma unroll
  for (int o = 0; o < 4; o++)
#pragma unroll
    for (int i = 0; i < 2; i++)
#pragma unroll
      for (int j = 0; j < 2; j++) acc[o][i][j] = z4;

  for (int ks = 0; ks < 8; ks++) {
    if (ks) __syncthreads();
    const int kb = ks * 128;
    gload16(Agf + kb, lAf);  gload16(Agf + kb + 8192, lAf + 512);
    gload16(Agr + kb, lAr);  gload16(Agr + kb + 8192, lAr + 512);
    gload16(Bg0 + kb, l0);   gload16(Bg0 + kb + 8192, l0 + 512);
    gload16(Bg1 + kb, l1);   gload16(Bg1 + kb + 8192, l1 + 512);
    gload16(Bg2 + kb, l2);   gload16(Bg2 + kb + 8192, l2 + 512);
    gload16(Bg3 + kb, l3);   gload16(Bg3 + kb + 8192, l3 + 512);
    __syncthreads();
#pragma unroll
    for (int ch = 0; ch < 2; ch++) {
      const int cq = ch * 4 + quad;
      bf16x8 af0 = lds_frag(Atf, wm * 32 + c, cq);
      bf16x8 af1 = lds_frag(Atf, wm * 32 + 16 + c, cq);
      bf16x8 ar0 = lds_frag(Atr, wm * 32 + c, cq);
      bf16x8 ar1 = lds_frag(Atr, wm * 32 + 16 + c, cq);
#pragma unroll
      for (int nt = 0; nt < 2; nt++) {
        const int rb = wn * 32 + nt * 16 + c;
        bf16x8 f0 = lds_frag(Bfh, rb, cq);
        bf16x8 f1 = lds_frag(Bfg, rb, cq);
        bf16x8 f2 = lds_frag(Brh, rb, cq);
        bf16x8 f3 = lds_frag(Brg, rb, cq);
        acc[0][0][nt] = __builtin_amdgcn_mfma_f32_16x16x32_bf16(af0, f0, acc[0][0][nt], 0, 0, 0);
        acc[0][1][nt] = __builtin_amdgcn_mfma_f32_16x16x32_bf16(af1, f0, acc[0][1][nt], 0, 0, 0);
        acc[1][0][nt] = __builtin_amdgcn_mfma_f32_16x16x32_bf16(af0, f1, acc[1][0][nt], 0, 0, 0);
        acc[1][1][nt] = __builtin_amdgcn_mfma_f32_16x16x32_bf16(af1, f1, acc[1][1][nt], 0, 0, 0);
        acc[2][0][nt] = __builtin_amdgcn_mfma_f32_16x16x32_bf16(ar0, f2, acc[2][0][nt], 0, 0, 0);
        acc[2][1][nt] = __builtin_amdgcn_mfma_f32_16x16x32_bf16(ar1, f2, acc[2][1][nt], 0, 0, 0);
        acc[3][0][nt] = __builtin_amdgcn_mfma_f32_16x16x32_bf16(ar0, f3, acc[3][0][nt], 0, 0, 0);
        acc[3][1][nt] = __builtin_amdgcn_mfma_f32_16x16x32_bf16(ar1, f3, acc[3][1][nt], 0, 0, 0);
      }
    }
  }

#pragma unroll
  for (int ms = 0; ms < 2; ms++)
#pragma unroll
    for (int nt = 0; nt < 2; nt++) {
      int n = n0 + wn * 32 + nt * 16 + c;
      float b0 = bfh[n], b1 = bfg[n], b2 = brh[n], b3 = brg[n];
      int t0 = m0 + wm * 32 + ms * 16 + quad * 4;
#pragma unroll
      for (int r = 0; r < 4; r++) {
        int t = t0 + r;
        float Ff = acc[0][ms][nt][r] + b0;
        float Gf = 1.0f / (1.0f + __expf(-(acc[1][ms][nt][r] + b1)));
        float Fr = acc[2][ms][nt][r] + b2;
        float Gr = 1.0f / (1.0f + __expf(-(acc[3][ms][nt][r] + b3)));
        float ef = __expf(Gf), er = __expf(Gr);
        out[(size_t)t * 512 + n] = (Ff * ef + Fr * er) / (ef + er);
      }
    }
}

// ---------------------------------------------------------------------------
// Launch. Workspace layout (bytes):
//   0: xb 4MB | 4: Qb 4MB | 8: Kb 4MB | 12: Vtb 4MB | 16: Tfb 4MB | 20: Trb 4MB
//   24: wt 3.5MB | 28: Mu8 4MB | 32: invZg 128KB
// ---------------------------------------------------------------------------
extern "C" void kernel_launch(void* const* d_in, const int* in_sizes, int n_in,
                              void* d_out, int out_size, void* d_ws, size_t ws_size,
                              hipStream_t stream) {
  const float* x   = (const float*)d_in[0];
  const float* Wq  = (const float*)d_in[1];
  const float* bq  = (const float*)d_in[2];
  const float* Wk  = (const float*)d_in[3];
  const float* bk  = (const float*)d_in[4];
  const float* Wv  = (const float*)d_in[5];
  const float* bv  = (const float*)d_in[6];
  const float* cw  = (const float*)d_in[7];
  const float* cb  = (const float*)d_in[8];
  const float* Wfh = (const float*)d_in[9];
  const float* bfh = (const float*)d_in[10];
  const float* Wfg = (const float*)d_in[11];
  const float* bfg = (const float*)d_in[12];
  const float* Wrh = (const float*)d_in[13];
  const float* brh = (const float*)d_in[14];
  const float* Wrg = (const float*)d_in[15];
  const float* brg = (const float*)d_in[16];

  char* ws = (char*)d_ws;
  const size_t MB = 1024 * 1024;
  unsigned short* xb  = (unsigned short*)(ws + 0 * MB);
  unsigned short* Qb  = (unsigned short*)(ws + 4 * MB);
  unsigned short* Kb  = (unsigned short*)(ws + 8 * MB);
  unsigned short* Vtb = (unsigned short*)(ws + 12 * MB);
  unsigned short* Tfb = (unsigned short*)(ws + 16 * MB);
  unsigned short* Trb = (unsigned short*)(ws + 20 * MB);
  unsigned short* wt  = (unsigned short*)(ws + 24 * MB);
  unsigned char*  Mu8 = (unsigned char*)(ws + 28 * MB);
  float*          invZg = (float*)(ws + 32 * MB);
  const size_t WSZ = 512 * 512;

  prep_kernel<<<512, 256, 0, stream>>>(x, Wq, Wk, Wv, Wfh, Wfg, Wrh, Wrg, xb, wt);
  qkv_kernel<<<dim3(64, 8), 256, 0, stream>>>(xb, wt + 0 * WSZ, wt + 1 * WSZ, wt + 2 * WSZ,
                                              bq, bk, bv, Qb, Kb, Vtb);
  zmask_kernel<<<dim3(64, 4), 512, 0, stream>>>(Qb, Kb, cw, cb, Mu8, invZg);
  pv_kernel<<<dim3(16, 8, 4), 256, 0, stream>>>(Qb, Kb, Vtb, Mu8, invZg, Tfb, Trb);
  final_kernel<<<dim3(64, 8), 256, 0, stream>>>(Tfb, Trb, wt + 3 * WSZ, wt + 4 * WSZ,
                                                wt + 5 * WSZ, wt + 6 * WSZ,
                                                bfh, bfg, brh, brg, (float*)d_out);
}